// Round 11
// baseline (143.147 us; speedup 1.0000x reference)
//
#include <hip/hip_runtime.h>
#include <stdint.h>

typedef __attribute__((ext_vector_type(8))) short short8v;
typedef __attribute__((ext_vector_type(4))) float float4v;

__device__ __forceinline__ unsigned short f32_to_bf16(float f) {
    union { float f; uint32_t u; } v; v.f = f;
    uint32_t u = v.u;
    u += 0x7FFFu + ((u >> 16) & 1u);
    return (unsigned short)(u >> 16);
}

#define T_LEN 4096
#define C_DIM 1024
#define HSZ 64

// ---------------- kernel 0: W -> Wt (bf16, transposed [192][1024]) ----------------
__global__ void wt_kernel(const float* __restrict__ Wq, const float* __restrict__ Wk,
                          const float* __restrict__ Wv, unsigned short* __restrict__ Wt) {
    int tid = blockIdx.x * blockDim.x + threadIdx.x;   // 0 .. 3*65536-1
    int m   = tid >> 16;
    int rem = tid & 65535;
    int kk  = rem >> 6;
    int col = rem & 63;
    const float* W = (m == 0) ? Wq : ((m == 1) ? Wk : Wv);
    Wt[(size_t)m * 65536 + (size_t)col * 1024 + kk] = f32_to_bf16(W[(size_t)kk * 64 + col]);
}

// ---------------- kernel 1: streaming QKV projection ----------------
// No x staging: A-frags built directly from global fp32 x (L1/L2 absorb the
// 4x output-triple reuse). 8 waves = 4 output-triples x 2 K-halves; fp32
// split-K combine via LDS (R8-verified). XCD-pinned row mapping (R9).
__global__ __launch_bounds__(512) void qkv_kernel(
    const float* __restrict__ x, const unsigned short* __restrict__ Wt,
    unsigned short* __restrict__ qo, unsigned short* __restrict__ ko,
    unsigned short* __restrict__ vto)
{
    __shared__ float part[4][3][64][4];   // 12 KB: [wq][t][lane][j]
    const int tid = threadIdx.x;
    const int bid = (int)blockIdx.x;
    const int rowidx = (((bid >> 1) & 3) << 8) + ((bid >> 3) << 1) + (bid & 1);
    const int row0 = rowidx * 16;

    const int wave = tid >> 6, lane = tid & 63;
    const int wq = wave & 3, wh = wave >> 2;   // output triple / K-half
    const int g = lane >> 4, c = lane & 15;

    const float* xrow = x + (size_t)(row0 + c) * 1024;
    const unsigned short* w0 = Wt + (size_t)((wq * 3 + 0) * 16 + c) * 1024;
    const unsigned short* w1 = Wt + (size_t)((wq * 3 + 1) * 16 + c) * 1024;
    const unsigned short* w2 = Wt + (size_t)((wq * 3 + 2) * 16 + c) * 1024;

    float4v acc0 = {0,0,0,0}, acc1 = {0,0,0,0}, acc2 = {0,0,0,0};
    #pragma unroll 4
    for (int i = 0; i < 16; ++i) {
        const int koff = (wh * 16 + i) * 32 + g * 8;
        const float4 xa = *(const float4*)(xrow + koff);
        const float4 xb = *(const float4*)(xrow + koff + 4);
        union { unsigned short s[8]; short8v v; } a;
        a.s[0] = f32_to_bf16(xa.x); a.s[1] = f32_to_bf16(xa.y);
        a.s[2] = f32_to_bf16(xa.z); a.s[3] = f32_to_bf16(xa.w);
        a.s[4] = f32_to_bf16(xb.x); a.s[5] = f32_to_bf16(xb.y);
        a.s[6] = f32_to_bf16(xb.z); a.s[7] = f32_to_bf16(xb.w);
        const short8v b0 = *(const short8v*)(w0 + koff);
        const short8v b1 = *(const short8v*)(w1 + koff);
        const short8v b2 = *(const short8v*)(w2 + koff);
        acc0 = __builtin_amdgcn_mfma_f32_16x16x32_bf16(a.v, b0, acc0, 0, 0, 0);
        acc1 = __builtin_amdgcn_mfma_f32_16x16x32_bf16(a.v, b1, acc1, 0, 0, 0);
        acc2 = __builtin_amdgcn_mfma_f32_16x16x32_bf16(a.v, b2, acc2, 0, 0, 0);
    }

    // split-K combine through LDS (fp32), then epilogue on wh==0 waves
    float4v accs[3] = {acc0, acc1, acc2};
    if (wh == 1) {
        #pragma unroll
        for (int t = 0; t < 3; ++t)
            #pragma unroll
            for (int j = 0; j < 4; ++j)
                part[wq][t][lane][j] = accs[t][j];
    }
    __syncthreads();
    if (wh == 0) {
        #pragma unroll
        for (int t = 0; t < 3; ++t) {
            #pragma unroll
            for (int j = 0; j < 4; ++j)
                accs[t][j] += part[wq][t][lane][j];
            int ct = wq * 3 + t;
            int m = ct >> 2, hcol = (ct & 3) * 16 + c;
            if (m == 2) {
                // vT[b][hcol][t_global]
                #pragma unroll
                for (int j = 0; j < 4; ++j) {
                    int r = row0 + g * 4 + j;
                    vto[((size_t)(r >> 12) * 64 + hcol) * 4096 + (r & 4095)] = f32_to_bf16(accs[t][j]);
                }
            } else {
                unsigned short* dst = (m == 0) ? qo : ko;
                float sc = (m == 0) ? 0.125f : 1.0f;   // fold 1/sqrt(64) into q
                #pragma unroll
                for (int j = 0; j < 4; ++j)
                    dst[(size_t)(row0 + g * 4 + j) * 64 + hcol] = f32_to_bf16(accs[t][j] * sc);
            }
        }
    }
}

// ---------------- kernel 2: causal flash attention (R10, unchanged) ----------------
#define PLD 72

__global__ __launch_bounds__(512) void attn_kernel(
    const unsigned short* __restrict__ qi, const unsigned short* __restrict__ ki,
    const unsigned short* __restrict__ vt, float* __restrict__ out)
{
    __shared__ __align__(16) unsigned short Ps[8][16 * PLD];  // per-wave P buffer
    __shared__ float CombO[6][16][64];                        // [slot][q-row][d]
    __shared__ float CombM[6][16];
    __shared__ float CombL[6][16];

    const int tid   = threadIdx.x;
    const int wave  = tid >> 6, lane = tid & 63;
    const int qh    = wave & 1, slice = wave >> 1;
    const int g = lane >> 4, c = lane & 15;

    const int bid   = (int)blockIdx.x;
    const int batch = (bid >> 1) & 3;     // XCD pair {2b,2b+1} = batch b
    const int q0    = bid & 1;
    const int m_    = bid >> 3;
    const int mm    = m_ & 31;
    const int qb = q0 ? ((m_ < 32) ? 2 * mm + 1 : 126 - 2 * mm)
                      : ((m_ < 32) ? 2 * mm     : 127 - 2 * mm);

    const int rbase = qb * 32 + qh * 16;
    const size_t bo = (size_t)batch * T_LEN * HSZ;

    short8v qf0 = *(const short8v*)(qi + bo + (size_t)(rbase + c) * 64 +  0 + g * 8);
    short8v qf1 = *(const short8v*)(qi + bo + (size_t)(rbase + c) * 64 + 32 + g * 8);

    float4v acc[4];   // acc[dt][j] = O^T[dt*16+g*4+j][q=rbase+c]
    #pragma unroll
    for (int i2 = 0; i2 < 4; ++i2) acc[i2] = (float4v){0,0,0,0};
    float mrow = -3e38f;   // per-lane: q = rbase+c
    float lsum = 0.f;

    const int nt_w = ((rbase + 15) >> 6) + 1;
    unsigned short* Pw = &Ps[wave][0];

    for (int t = slice; t < nt_w; t += 4) {
        const int s0 = t * 64;

        // ---- S^T = K Q^T : sa[ct][j] = S[q=rbase+c][k=s0+ct*16+g*4+j] ----
        float4v sa[4];
        #pragma unroll
        for (int ct = 0; ct < 4; ++ct) {
            const unsigned short* krow = ki + bo + (size_t)(s0 + ct * 16 + c) * 64;
            short8v b0 = *(const short8v*)(krow +  0 + g * 8);
            short8v b1 = *(const short8v*)(krow + 32 + g * 8);
            float4v z = {0, 0, 0, 0};
            z = __builtin_amdgcn_mfma_f32_16x16x32_bf16(b0, qf0, z, 0, 0, 0);
            sa[ct] = __builtin_amdgcn_mfma_f32_16x16x32_bf16(b1, qf1, z, 0, 0, 0);
        }

        // ---- issue first half of vT A-frags (latency hides under softmax) ----
        short8v vf0[4];
        #pragma unroll
        for (int ct = 0; ct < 4; ++ct)
            vf0[ct] = *(const short8v*)(vt + bo + (size_t)(ct * 16 + c) * 4096 + s0 + 0 + g * 8);

        // ---- causal mask: k = s0+ct*16+g*4+j  vs  q = rbase+c ----
        if (s0 + 63 > rbase) {
            #pragma unroll
            for (int ct = 0; ct < 4; ++ct)
                #pragma unroll
                for (int j = 0; j < 4; ++j)
                    if (s0 + ct * 16 + g * 4 + j > rbase + c) sa[ct][j] = -3e38f;
        }

        // ---- online softmax: lane-local max tree + 2 shfl ----
        float mx01 = fmaxf(fmaxf(sa[0][0], sa[0][1]), fmaxf(sa[0][2], sa[0][3]));
        float mx11 = fmaxf(fmaxf(sa[1][0], sa[1][1]), fmaxf(sa[1][2], sa[1][3]));
        float mx21 = fmaxf(fmaxf(sa[2][0], sa[2][1]), fmaxf(sa[2][2], sa[2][3]));
        float mx31 = fmaxf(fmaxf(sa[3][0], sa[3][1]), fmaxf(sa[3][2], sa[3][3]));
        float mx = fmaxf(fmaxf(mx01, mx11), fmaxf(mx21, mx31));
        mx = fmaxf(mx, __shfl_xor(mx, 16, 64));
        mx = fmaxf(mx, __shfl_xor(mx, 32, 64));
        const float nm = fmaxf(mrow, mx);
        const float al = __expf(mrow - nm);
        mrow = nm;
        float ps = 0.f;
        #pragma unroll
        for (int ct = 0; ct < 4; ++ct)
            #pragma unroll
            for (int j = 0; j < 4; ++j) {
                float p = __expf(sa[ct][j] - nm);
                sa[ct][j] = p;
                ps += p;
            }
        lsum = lsum * al + ps;
        #pragma unroll
        for (int dt = 0; dt < 4; ++dt)
            #pragma unroll
            for (int j = 0; j < 4; ++j) acc[dt][j] *= al;

        // ---- P^T (lane-local rows) -> per-wave LDS: Pw[q=c][k] ----
        #pragma unroll
        for (int ct = 0; ct < 4; ++ct)
            #pragma unroll
            for (int j = 0; j < 4; ++j)
                Pw[c * PLD + ct * 16 + g * 4 + j] = f32_to_bf16(sa[ct][j]);

        // ---- second half of vT A-frags ----
        short8v vf1[4];
        #pragma unroll
        for (int ct = 0; ct < 4; ++ct)
            vf1[ct] = *(const short8v*)(vt + bo + (size_t)(ct * 16 + c) * 4096 + s0 + 32 + g * 8);

        // ---- P B-frags ----
        short8v pa0 = *(const short8v*)(&Pw[c * PLD +  0 + g * 8]);
        short8v pa1 = *(const short8v*)(&Pw[c * PLD + 32 + g * 8]);

        // ---- O^T += vT P^T ----
        #pragma unroll
        for (int dt = 0; dt < 4; ++dt)
            acc[dt] = __builtin_amdgcn_mfma_f32_16x16x32_bf16(vf0[dt], pa0, acc[dt], 0, 0, 0);
        #pragma unroll
        for (int dt = 0; dt < 4; ++dt)
            acc[dt] = __builtin_amdgcn_mfma_f32_16x16x32_bf16(vf1[dt], pa1, acc[dt], 0, 0, 0);
    }

    // ---- reduce row sum across the 4 g-lanes (same q=c) ----
    lsum += __shfl_xor(lsum, 16, 64);
    lsum += __shfl_xor(lsum, 32, 64);

    // ---- cross-slice combine ----
    if (slice > 0) {
        const int sidx = (slice - 1) * 2 + qh;
        #pragma unroll
        for (int dt = 0; dt < 4; ++dt)
            #pragma unroll
            for (int j = 0; j < 4; ++j)
                CombO[sidx][c][dt * 16 + g * 4 + j] = acc[dt][j];
        if (g == 0) {
            CombM[sidx][c] = mrow;
            CombL[sidx][c] = lsum;
        }
    }
    __syncthreads();

    if (slice == 0) {
        float M = mrow;
        #pragma unroll
        for (int s = 0; s < 3; ++s) M = fmaxf(M, CombM[s * 2 + qh][c]);
        const float a0 = __expf(mrow - M);
        float as[3];
        float lt = lsum * a0;
        #pragma unroll
        for (int s = 0; s < 3; ++s) {
            as[s] = __expf(CombM[s * 2 + qh][c] - M);
            lt += as[s] * CombL[s * 2 + qh][c];
        }
        const float linv = 1.0f / lt;
        #pragma unroll
        for (int dt = 0; dt < 4; ++dt) {
            float4 o;
            float* op = &o.x;
            #pragma unroll
            for (int j = 0; j < 4; ++j) {
                float v = acc[dt][j] * a0;
                #pragma unroll
                for (int s = 0; s < 3; ++s)
                    v += as[s] * CombO[s * 2 + qh][c][dt * 16 + g * 4 + j];
                op[j] = v * linv;
            }
            *(float4*)(out + bo + (size_t)(rbase + c) * 64 + dt * 16 + g * 4) = o;
        }
    }
}

extern "C" void kernel_launch(void* const* d_in, const int* in_sizes, int n_in,
                              void* d_out, int out_size, void* d_ws, size_t ws_size,
                              hipStream_t stream) {
    const float* x  = (const float*)d_in[0];
    const float* Wq = (const float*)d_in[1];
    const float* Wk = (const float*)d_in[2];
    const float* Wv = (const float*)d_in[3];

    unsigned short* Wt = (unsigned short*)d_ws;                        // 384 KiB
    unsigned short* q  = (unsigned short*)((char*)d_ws + (size_t)3 * 65536 * 2);
    unsigned short* k  = q + (size_t)4 * T_LEN * HSZ;
    unsigned short* vT = k + (size_t)4 * T_LEN * HSZ;                  // [B][64][4096]
    float* out = (float*)d_out;

    hipLaunchKernelGGL(wt_kernel,  dim3(768), dim3(256), 0, stream, Wq, Wk, Wv, Wt);
    hipLaunchKernelGGL(qkv_kernel, dim3(1024), dim3(512), 0, stream, x, Wt, q, k, vT);
    hipLaunchKernelGGL(attn_kernel, dim3(512), dim3(512), 0, stream, q, k, vT, out);
}

// Round 12
// 73.171 us; speedup vs baseline: 1.9563x; 1.9563x over previous
//
#include <hip/hip_runtime.h>
#include <stdint.h>

typedef __attribute__((ext_vector_type(8))) short short8v;
typedef __attribute__((ext_vector_type(4))) float float4v;

__device__ __forceinline__ unsigned short f32_to_bf16(float f) {
    union { float f; uint32_t u; } v; v.f = f;
    uint32_t u = v.u;
    u += 0x7FFFu + ((u >> 16) & 1u);
    return (unsigned short)(u >> 16);
}

#define T_LEN 4096
#define C_DIM 1024
#define HSZ 64

// ---------------- kernel 0: W -> Wtp (bf16, FRAGMENT-MAJOR) ----------------
// Wtp[((ct*32+ks)*64 + lane)*8 + e] = W_{ct>>2}[ks*32+(lane>>4)*8+e][(ct&3)*16+(lane&15)]
// so a wave's B-frag for (ct,ks) is one contiguous 1 KB read.
__global__ void wt_kernel(const float* __restrict__ Wq, const float* __restrict__ Wk,
                          const float* __restrict__ Wv, unsigned short* __restrict__ Wtp) {
    int idx = blockIdx.x * blockDim.x + threadIdx.x;   // 0 .. 196607
    int e    = idx & 7;
    int lane = (idx >> 3) & 63;
    int ks   = (idx >> 9) & 31;
    int ct   = idx >> 14;
    int g = lane >> 4, c = lane & 15;
    int k   = ks * 32 + g * 8 + e;
    int col = (ct & 3) * 16 + c;
    int m   = ct >> 2;
    const float* W = (m == 0) ? Wq : ((m == 1) ? Wk : Wv);
    Wtp[idx] = f32_to_bf16(W[(size_t)k * 64 + col]);
}

// ---------------- kernel 1: fused QKV projection (staged x, frag-major Wtp) ----------------
// q, k written [B*T][64] row-major; v written FRAGMENT-MAJOR vp (see attn).
#define XLD 1032   // 1024 + 8 pad

__global__ __launch_bounds__(256) void qkv_kernel(
    const float* __restrict__ x, const unsigned short* __restrict__ Wtp,
    unsigned short* __restrict__ qo, unsigned short* __restrict__ ko,
    unsigned short* __restrict__ vp)
{
    __shared__ __align__(16) unsigned short xs[16 * XLD];
    const int tid = threadIdx.x;
    const int bid = (int)blockIdx.x;
    const int rowidx = (((bid >> 1) & 3) << 8) + ((bid >> 3) << 1) + (bid & 1);
    const int row0 = rowidx * 16;

    #pragma unroll
    for (int i = 0; i < 16; ++i) {
        int f   = i * 256 + tid;           // float4 index, 4096 total
        int row = f >> 8, c4 = f & 255;
        const float4 val = *((const float4*)x + (size_t)(row0 + row) * 256 + c4);
        union { unsigned short s[4]; uint64_t u; } pk;
        pk.s[0] = f32_to_bf16(val.x); pk.s[1] = f32_to_bf16(val.y);
        pk.s[2] = f32_to_bf16(val.z); pk.s[3] = f32_to_bf16(val.w);
        *(uint64_t*)(&xs[row * XLD + c4 * 4]) = pk.u;
    }
    __syncthreads();

    const int wave = tid >> 6, lane = tid & 63;
    const int g = lane >> 4, c = lane & 15;

    float4v acc0 = {0,0,0,0}, acc1 = {0,0,0,0}, acc2 = {0,0,0,0};
    const unsigned short* wp0 = Wtp + (size_t)((wave * 3 + 0) * 32) * 512 + lane * 8;
    const unsigned short* wp1 = Wtp + (size_t)((wave * 3 + 1) * 32) * 512 + lane * 8;
    const unsigned short* wp2 = Wtp + (size_t)((wave * 3 + 2) * 32) * 512 + lane * 8;
    #pragma unroll 4
    for (int ks = 0; ks < 32; ++ks) {
        const int koff = ks * 32 + g * 8;
        short8v a  = *(const short8v*)(&xs[c * XLD + koff]);
        short8v b0 = *(const short8v*)(wp0 + ks * 512);   // contiguous 1 KB / wave
        short8v b1 = *(const short8v*)(wp1 + ks * 512);
        short8v b2 = *(const short8v*)(wp2 + ks * 512);
        acc0 = __builtin_amdgcn_mfma_f32_16x16x32_bf16(a, b0, acc0, 0, 0, 0);
        acc1 = __builtin_amdgcn_mfma_f32_16x16x32_bf16(a, b1, acc1, 0, 0, 0);
        acc2 = __builtin_amdgcn_mfma_f32_16x16x32_bf16(a, b2, acc2, 0, 0, 0);
    }

    float4v accs[3] = {acc0, acc1, acc2};
    #pragma unroll
    for (int t = 0; t < 3; ++t) {
        int ct = wave * 3 + t;
        int m = ct >> 2, hcol = (ct & 3) * 16 + c;
        if (m == 2) {
            // v -> fragment-major vp: element v[b][s][d] at
            // vp[b*262144 + (s>>5)*2048 + (ct&3)*512 + (((s>>3)&3)*16 + c)*8 + (s&7)]
            // for fixed (g): j=0..3 are 4 consecutive e -> one 8B store.
            const int r0 = row0 + g * 4;                  // global row of j=0
            const int b  = r0 >> 12;
            const int s0_ = r0 & 4095;
            const int t2h = s0_ >> 5;
            const int gv  = (s0_ >> 3) & 3;
            const int e0  = s0_ & 7;                      // 0 or 4
            union { unsigned short s[4]; uint64_t u; } pk;
            #pragma unroll
            for (int j = 0; j < 4; ++j) pk.s[j] = f32_to_bf16(accs[t][j]);
            *(uint64_t*)(vp + (size_t)b * 262144 + t2h * 2048 + (ct & 3) * 512
                            + (gv * 16 + c) * 8 + e0) = pk.u;
        } else {
            unsigned short* dst = (m == 0) ? qo : ko;
            float sc = (m == 0) ? 0.125f : 1.0f;   // fold 1/sqrt(64) into q
            #pragma unroll
            for (int j = 0; j < 4; ++j)
                dst[(size_t)(row0 + g * 4 + j) * 64 + hcol] = f32_to_bf16(accs[t][j] * sc);
        }
    }
}

// ---------------- kernel 2: causal flash attention (swapped QK^T, frag-major vp) ----------------
#define PLD 72

__global__ __launch_bounds__(512) void attn_kernel(
    const unsigned short* __restrict__ qi, const unsigned short* __restrict__ ki,
    const unsigned short* __restrict__ vp, float* __restrict__ out)
{
    __shared__ __align__(16) unsigned short Ps[8][16 * PLD];  // per-wave P buffer
    __shared__ float CombO[6][16][64];                        // [slot][q-row][d]
    __shared__ float CombM[6][16];
    __shared__ float CombL[6][16];

    const int tid   = threadIdx.x;
    const int wave  = tid >> 6, lane = tid & 63;
    const int qh    = wave & 1, slice = wave >> 1;
    const int g = lane >> 4, c = lane & 15;

    const int bid   = (int)blockIdx.x;
    const int batch = (bid >> 1) & 3;     // XCD pair {2b,2b+1} = batch b
    const int q0    = bid & 1;
    const int m_    = bid >> 3;
    const int mm    = m_ & 31;
    const int qb = q0 ? ((m_ < 32) ? 2 * mm + 1 : 126 - 2 * mm)
                      : ((m_ < 32) ? 2 * mm     : 127 - 2 * mm);

    const int rbase = qb * 32 + qh * 16;
    const size_t bo  = (size_t)batch * T_LEN * HSZ;
    const size_t bov = (size_t)batch * 262144;

    short8v qf0 = *(const short8v*)(qi + bo + (size_t)(rbase + c) * 64 +  0 + g * 8);
    short8v qf1 = *(const short8v*)(qi + bo + (size_t)(rbase + c) * 64 + 32 + g * 8);

    float4v acc[4];   // acc[dt][j] = O^T[dt*16+g*4+j][q=rbase+c]
    #pragma unroll
    for (int i2 = 0; i2 < 4; ++i2) acc[i2] = (float4v){0,0,0,0};
    float mrow = -3e38f;   // per-lane: q = rbase+c
    float lsum = 0.f;

    const int nt_w = ((rbase + 15) >> 6) + 1;
    unsigned short* Pw = &Ps[wave][0];

    for (int t = slice; t < nt_w; t += 4) {
        const int s0 = t * 64;

        // ---- S^T = K Q^T : sa[ct][j] = S[q=rbase+c][k=s0+ct*16+g*4+j] ----
        float4v sa[4];
        #pragma unroll
        for (int ct = 0; ct < 4; ++ct) {
            const unsigned short* krow = ki + bo + (size_t)(s0 + ct * 16 + c) * 64;
            short8v b0 = *(const short8v*)(krow +  0 + g * 8);
            short8v b1 = *(const short8v*)(krow + 32 + g * 8);
            float4v z = {0, 0, 0, 0};
            z = __builtin_amdgcn_mfma_f32_16x16x32_bf16(b0, qf0, z, 0, 0, 0);
            sa[ct] = __builtin_amdgcn_mfma_f32_16x16x32_bf16(b1, qf1, z, 0, 0, 0);
        }

        // ---- first-half vp A-frags: contiguous 1 KB / wave ----
        short8v vf0[4];
        #pragma unroll
        for (int dt = 0; dt < 4; ++dt)
            vf0[dt] = *(const short8v*)(vp + bov + (size_t)((t * 2 + 0) * 4 + dt) * 512 + lane * 8);

        // ---- causal mask: k = s0+ct*16+g*4+j  vs  q = rbase+c ----
        if (s0 + 63 > rbase) {
            #pragma unroll
            for (int ct = 0; ct < 4; ++ct)
                #pragma unroll
                for (int j = 0; j < 4; ++j)
                    if (s0 + ct * 16 + g * 4 + j > rbase + c) sa[ct][j] = -3e38f;
        }

        // ---- online softmax: lane-local max tree + 2 shfl ----
        float mx01 = fmaxf(fmaxf(sa[0][0], sa[0][1]), fmaxf(sa[0][2], sa[0][3]));
        float mx11 = fmaxf(fmaxf(sa[1][0], sa[1][1]), fmaxf(sa[1][2], sa[1][3]));
        float mx21 = fmaxf(fmaxf(sa[2][0], sa[2][1]), fmaxf(sa[2][2], sa[2][3]));
        float mx31 = fmaxf(fmaxf(sa[3][0], sa[3][1]), fmaxf(sa[3][2], sa[3][3]));
        float mx = fmaxf(fmaxf(mx01, mx11), fmaxf(mx21, mx31));
        mx = fmaxf(mx, __shfl_xor(mx, 16, 64));
        mx = fmaxf(mx, __shfl_xor(mx, 32, 64));
        const float nm = fmaxf(mrow, mx);
        const float al = __expf(mrow - nm);
        mrow = nm;
        float ps = 0.f;
        #pragma unroll
        for (int ct = 0; ct < 4; ++ct)
            #pragma unroll
            for (int j = 0; j < 4; ++j) {
                float p = __expf(sa[ct][j] - nm);
                sa[ct][j] = p;
                ps += p;
            }
        lsum = lsum * al + ps;
        #pragma unroll
        for (int dt = 0; dt < 4; ++dt)
            #pragma unroll
            for (int j = 0; j < 4; ++j) acc[dt][j] *= al;

        // ---- P^T (lane-local rows) -> per-wave LDS: Pw[q=c][k] ----
        #pragma unroll
        for (int ct = 0; ct < 4; ++ct)
            #pragma unroll
            for (int j = 0; j < 4; ++j)
                Pw[c * PLD + ct * 16 + g * 4 + j] = f32_to_bf16(sa[ct][j]);

        // ---- second-half vp A-frags ----
        short8v vf1[4];
        #pragma unroll
        for (int dt = 0; dt < 4; ++dt)
            vf1[dt] = *(const short8v*)(vp + bov + (size_t)((t * 2 + 1) * 4 + dt) * 512 + lane * 8);

        // ---- P B-frags ----
        short8v pa0 = *(const short8v*)(&Pw[c * PLD +  0 + g * 8]);
        short8v pa1 = *(const short8v*)(&Pw[c * PLD + 32 + g * 8]);

        // ---- O^T += vT P^T ----
        #pragma unroll
        for (int dt = 0; dt < 4; ++dt)
            acc[dt] = __builtin_amdgcn_mfma_f32_16x16x32_bf16(vf0[dt], pa0, acc[dt], 0, 0, 0);
        #pragma unroll
        for (int dt = 0; dt < 4; ++dt)
            acc[dt] = __builtin_amdgcn_mfma_f32_16x16x32_bf16(vf1[dt], pa1, acc[dt], 0, 0, 0);
    }

    // ---- reduce row sum across the 4 g-lanes (same q=c) ----
    lsum += __shfl_xor(lsum, 16, 64);
    lsum += __shfl_xor(lsum, 32, 64);

    // ---- cross-slice combine ----
    if (slice > 0) {
        const int sidx = (slice - 1) * 2 + qh;
        #pragma unroll
        for (int dt = 0; dt < 4; ++dt)
            #pragma unroll
            for (int j = 0; j < 4; ++j)
                CombO[sidx][c][dt * 16 + g * 4 + j] = acc[dt][j];
        if (g == 0) {
            CombM[sidx][c] = mrow;
            CombL[sidx][c] = lsum;
        }
    }
    __syncthreads();

    if (slice == 0) {
        float M = mrow;
        #pragma unroll
        for (int s = 0; s < 3; ++s) M = fmaxf(M, CombM[s * 2 + qh][c]);
        const float a0 = __expf(mrow - M);
        float as[3];
        float lt = lsum * a0;
        #pragma unroll
        for (int s = 0; s < 3; ++s) {
            as[s] = __expf(CombM[s * 2 + qh][c] - M);
            lt += as[s] * CombL[s * 2 + qh][c];
        }
        const float linv = 1.0f / lt;
        #pragma unroll
        for (int dt = 0; dt < 4; ++dt) {
            float4 o;
            float* op = &o.x;
            #pragma unroll
            for (int j = 0; j < 4; ++j) {
                float v = acc[dt][j] * a0;
                #pragma unroll
                for (int s = 0; s < 3; ++s)
                    v += as[s] * CombO[s * 2 + qh][c][dt * 16 + g * 4 + j];
                op[j] = v * linv;
            }
            *(float4*)(out + bo + (size_t)(rbase + c) * 64 + dt * 16 + g * 4) = o;
        }
    }
}

extern "C" void kernel_launch(void* const* d_in, const int* in_sizes, int n_in,
                              void* d_out, int out_size, void* d_ws, size_t ws_size,
                              hipStream_t stream) {
    const float* x  = (const float*)d_in[0];
    const float* Wq = (const float*)d_in[1];
    const float* Wk = (const float*)d_in[2];
    const float* Wv = (const float*)d_in[3];

    unsigned short* Wt = (unsigned short*)d_ws;                        // 384 KiB (frag-major)
    unsigned short* q  = (unsigned short*)((char*)d_ws + (size_t)3 * 65536 * 2);
    unsigned short* k  = q + (size_t)4 * T_LEN * HSZ;
    unsigned short* vp = k + (size_t)4 * T_LEN * HSZ;                  // frag-major v, 2 MiB
    float* out = (float*)d_out;

    hipLaunchKernelGGL(wt_kernel,  dim3(768), dim3(256), 0, stream, Wq, Wk, Wv, Wt);
    hipLaunchKernelGGL(qkv_kernel, dim3(1024), dim3(256), 0, stream, x, Wt, q, k, vp);
    hipLaunchKernelGGL(attn_kernel, dim3(512), dim3(512), 0, stream, q, k, vp, out);
}

// Round 13
// 67.530 us; speedup vs baseline: 2.1198x; 1.0835x over previous
//
#include <hip/hip_runtime.h>
#include <stdint.h>

typedef __attribute__((ext_vector_type(8))) short short8v;
typedef __attribute__((ext_vector_type(4))) float float4v;

__device__ __forceinline__ unsigned short f32_to_bf16(float f) {
    union { float f; uint32_t u; } v; v.f = f;
    uint32_t u = v.u;
    u += 0x7FFFu + ((u >> 16) & 1u);
    return (unsigned short)(u >> 16);
}

#define T_LEN 4096
#define C_DIM 1024
#define HSZ 64

// ---------------- kernel 0: W -> Wtp (bf16, FRAGMENT-MAJOR) ----------------
__global__ void wt_kernel(const float* __restrict__ Wq, const float* __restrict__ Wk,
                          const float* __restrict__ Wv, unsigned short* __restrict__ Wtp) {
    int idx = blockIdx.x * blockDim.x + threadIdx.x;   // 0 .. 196607
    int e    = idx & 7;
    int lane = (idx >> 3) & 63;
    int ks   = (idx >> 9) & 31;
    int ct   = idx >> 14;
    int g = lane >> 4, c = lane & 15;
    int k   = ks * 32 + g * 8 + e;
    int col = (ct & 3) * 16 + c;
    int m   = ct >> 2;
    const float* W = (m == 0) ? Wq : ((m == 1) ? Wk : Wv);
    Wtp[idx] = f32_to_bf16(W[(size_t)k * 64 + col]);
}

// ---------------- kernel 1: fused QKV projection (staged x, frag-major Wtp) ----------------
// q row-major; K and V written FRAGMENT-MAJOR (kp, vp) for attn's mfma frags.
#define XLD 1032   // 1024 + 8 pad

__global__ __launch_bounds__(256) void qkv_kernel(
    const float* __restrict__ x, const unsigned short* __restrict__ Wtp,
    unsigned short* __restrict__ qo, unsigned short* __restrict__ kp,
    unsigned short* __restrict__ vp)
{
    __shared__ __align__(16) unsigned short xs[16 * XLD];
    const int tid = threadIdx.x;
    const int bid = (int)blockIdx.x;
    const int rowidx = (((bid >> 1) & 3) << 8) + ((bid >> 3) << 1) + (bid & 1);
    const int row0 = rowidx * 16;

    #pragma unroll
    for (int i = 0; i < 16; ++i) {
        int f   = i * 256 + tid;           // float4 index, 4096 total
        int row = f >> 8, c4 = f & 255;
        const float4 val = *((const float4*)x + (size_t)(row0 + row) * 256 + c4);
        union { unsigned short s[4]; uint64_t u; } pk;
        pk.s[0] = f32_to_bf16(val.x); pk.s[1] = f32_to_bf16(val.y);
        pk.s[2] = f32_to_bf16(val.z); pk.s[3] = f32_to_bf16(val.w);
        *(uint64_t*)(&xs[row * XLD + c4 * 4]) = pk.u;
    }
    __syncthreads();

    const int wave = tid >> 6, lane = tid & 63;
    const int g = lane >> 4, c = lane & 15;

    float4v acc0 = {0,0,0,0}, acc1 = {0,0,0,0}, acc2 = {0,0,0,0};
    const unsigned short* wp0 = Wtp + (size_t)((wave * 3 + 0) * 32) * 512 + lane * 8;
    const unsigned short* wp1 = Wtp + (size_t)((wave * 3 + 1) * 32) * 512 + lane * 8;
    const unsigned short* wp2 = Wtp + (size_t)((wave * 3 + 2) * 32) * 512 + lane * 8;
    #pragma unroll 4
    for (int ks = 0; ks < 32; ++ks) {
        const int koff = ks * 32 + g * 8;
        short8v a  = *(const short8v*)(&xs[c * XLD + koff]);
        short8v b0 = *(const short8v*)(wp0 + ks * 512);   // contiguous 1 KB / wave
        short8v b1 = *(const short8v*)(wp1 + ks * 512);
        short8v b2 = *(const short8v*)(wp2 + ks * 512);
        acc0 = __builtin_amdgcn_mfma_f32_16x16x32_bf16(a, b0, acc0, 0, 0, 0);
        acc1 = __builtin_amdgcn_mfma_f32_16x16x32_bf16(a, b1, acc1, 0, 0, 0);
        acc2 = __builtin_amdgcn_mfma_f32_16x16x32_bf16(a, b2, acc2, 0, 0, 0);
    }

    float4v accs[3] = {acc0, acc1, acc2};
    #pragma unroll
    for (int t = 0; t < 3; ++t) {
        int ct = wave * 3 + t;
        int m = ct >> 2, hcol = (ct & 3) * 16 + c;
        if (m == 2) {
            // v -> fragment-major vp (R12-verified): j=0..3 -> one 8B store
            const int r0 = row0 + g * 4;
            const int b  = r0 >> 12;
            const int s0_ = r0 & 4095;
            const int t2h = s0_ >> 5;
            const int gv  = (s0_ >> 3) & 3;
            const int e0  = s0_ & 7;
            union { unsigned short s[4]; uint64_t u; } pk;
            #pragma unroll
            for (int j = 0; j < 4; ++j) pk.s[j] = f32_to_bf16(accs[t][j]);
            *(uint64_t*)(vp + (size_t)b * 262144 + t2h * 2048 + (ct & 3) * 512
                            + (gv * 16 + c) * 8 + e0) = pk.u;
        } else if (m == 1) {
            // K -> fragment-major kp: K[s][d] at frag f=(s>>6)*8+((s>>4)&3)*2+(d>>5),
            // lane ((d>>3)&3)*16+(s&15), elem d&7. (d = hcol fixed; s varies with j.)
            const int fbase = ((row0 & 4095) >> 6) * 8 + (((row0 & 4095) >> 4) & 3) * 2 + (hcol >> 5);
            const int b = row0 >> 12;
            unsigned short* kb = kp + (size_t)b * 262144 + (size_t)fbase * 512
                                 + (((hcol >> 3) & 3) * 16) * 8 + (hcol & 7);
            #pragma unroll
            for (int j = 0; j < 4; ++j)
                kb[(g * 4 + j) * 8] = f32_to_bf16(accs[t][j]);
        } else {
            float sc = 0.125f;   // fold 1/sqrt(64) into q
            #pragma unroll
            for (int j = 0; j < 4; ++j)
                qo[(size_t)(row0 + g * 4 + j) * 64 + hcol] = f32_to_bf16(accs[t][j] * sc);
        }
    }
}

// ---------------- kernel 2: causal flash attention (swapped QK^T, all-frag-major) ----------------
#define PLD 72

__global__ __launch_bounds__(512) void attn_kernel(
    const unsigned short* __restrict__ qi, const unsigned short* __restrict__ kp,
    const unsigned short* __restrict__ vp, float* __restrict__ out)
{
    __shared__ __align__(16) unsigned short Ps[8][16 * PLD];  // per-wave P buffer
    __shared__ float CombO[6][16][64];                        // [slot][q-row][d]
    __shared__ float CombM[6][16];
    __shared__ float CombL[6][16];

    const int tid   = threadIdx.x;
    const int wave  = tid >> 6, lane = tid & 63;
    const int qh    = wave & 1, slice = wave >> 1;
    const int g = lane >> 4, c = lane & 15;

    const int bid   = (int)blockIdx.x;
    const int batch = (bid >> 1) & 3;     // XCD pair {2b,2b+1} = batch b
    const int q0    = bid & 1;
    const int m_    = bid >> 3;
    const int mm    = m_ & 31;
    const int qb = q0 ? ((m_ < 32) ? 2 * mm + 1 : 126 - 2 * mm)
                      : ((m_ < 32) ? 2 * mm     : 127 - 2 * mm);

    const int rbase = qb * 32 + qh * 16;
    const size_t bo  = (size_t)batch * T_LEN * HSZ;
    const size_t bov = (size_t)batch * 262144;

    short8v qf0 = *(const short8v*)(qi + bo + (size_t)(rbase + c) * 64 +  0 + g * 8);
    short8v qf1 = *(const short8v*)(qi + bo + (size_t)(rbase + c) * 64 + 32 + g * 8);

    float4v acc[4];   // acc[dt][j] = O^T[dt*16+g*4+j][q=rbase+c]
    #pragma unroll
    for (int i2 = 0; i2 < 4; ++i2) acc[i2] = (float4v){0,0,0,0};
    float mrow = -3e38f;   // per-lane: q = rbase+c
    float lsum = 0.f;

    const int nt_w = ((rbase + 15) >> 6) + 1;
    unsigned short* Pw = &Ps[wave][0];

    for (int t = slice; t < nt_w; t += 4) {
        const int s0 = t * 64;

        // ---- S^T = K Q^T : kp A-frags, contiguous 1 KB / wave ----
        float4v sa[4];
        #pragma unroll
        for (int ct = 0; ct < 4; ++ct) {
            short8v b0 = *(const short8v*)(kp + bov + (size_t)(t * 8 + ct * 2 + 0) * 512 + lane * 8);
            short8v b1 = *(const short8v*)(kp + bov + (size_t)(t * 8 + ct * 2 + 1) * 512 + lane * 8);
            float4v z = {0, 0, 0, 0};
            z = __builtin_amdgcn_mfma_f32_16x16x32_bf16(b0, qf0, z, 0, 0, 0);
            sa[ct] = __builtin_amdgcn_mfma_f32_16x16x32_bf16(b1, qf1, z, 0, 0, 0);
        }

        // ---- first-half vp A-frags: contiguous 1 KB / wave ----
        short8v vf0[4];
        #pragma unroll
        for (int dt = 0; dt < 4; ++dt)
            vf0[dt] = *(const short8v*)(vp + bov + (size_t)((t * 2 + 0) * 4 + dt) * 512 + lane * 8);

        // ---- causal mask: k = s0+ct*16+g*4+j  vs  q = rbase+c ----
        if (s0 + 63 > rbase) {
            #pragma unroll
            for (int ct = 0; ct < 4; ++ct)
                #pragma unroll
                for (int j = 0; j < 4; ++j)
                    if (s0 + ct * 16 + g * 4 + j > rbase + c) sa[ct][j] = -3e38f;
        }

        // ---- online softmax: lane-local max tree + 2 shfl ----
        float mx01 = fmaxf(fmaxf(sa[0][0], sa[0][1]), fmaxf(sa[0][2], sa[0][3]));
        float mx11 = fmaxf(fmaxf(sa[1][0], sa[1][1]), fmaxf(sa[1][2], sa[1][3]));
        float mx21 = fmaxf(fmaxf(sa[2][0], sa[2][1]), fmaxf(sa[2][2], sa[2][3]));
        float mx31 = fmaxf(fmaxf(sa[3][0], sa[3][1]), fmaxf(sa[3][2], sa[3][3]));
        float mx = fmaxf(fmaxf(mx01, mx11), fmaxf(mx21, mx31));
        mx = fmaxf(mx, __shfl_xor(mx, 16, 64));
        mx = fmaxf(mx, __shfl_xor(mx, 32, 64));
        const float nm = fmaxf(mrow, mx);
        const float al = __expf(mrow - nm);
        mrow = nm;
        float ps = 0.f;
        #pragma unroll
        for (int ct = 0; ct < 4; ++ct)
            #pragma unroll
            for (int j = 0; j < 4; ++j) {
                float p = __expf(sa[ct][j] - nm);
                sa[ct][j] = p;
                ps += p;
            }
        lsum = lsum * al + ps;
        #pragma unroll
        for (int dt = 0; dt < 4; ++dt)
            #pragma unroll
            for (int j = 0; j < 4; ++j) acc[dt][j] *= al;

        // ---- P^T (lane-local rows) -> per-wave LDS: Pw[q=c][k] ----
        #pragma unroll
        for (int ct = 0; ct < 4; ++ct)
            #pragma unroll
            for (int j = 0; j < 4; ++j)
                Pw[c * PLD + ct * 16 + g * 4 + j] = f32_to_bf16(sa[ct][j]);

        // ---- second-half vp A-frags ----
        short8v vf1[4];
        #pragma unroll
        for (int dt = 0; dt < 4; ++dt)
            vf1[dt] = *(const short8v*)(vp + bov + (size_t)((t * 2 + 1) * 4 + dt) * 512 + lane * 8);

        // ---- P B-frags ----
        short8v pa0 = *(const short8v*)(&Pw[c * PLD +  0 + g * 8]);
        short8v pa1 = *(const short8v*)(&Pw[c * PLD + 32 + g * 8]);

        // ---- O^T += vT P^T ----
        #pragma unroll
        for (int dt = 0; dt < 4; ++dt)
            acc[dt] = __builtin_amdgcn_mfma_f32_16x16x32_bf16(vf0[dt], pa0, acc[dt], 0, 0, 0);
        #pragma unroll
        for (int dt = 0; dt < 4; ++dt)
            acc[dt] = __builtin_amdgcn_mfma_f32_16x16x32_bf16(vf1[dt], pa1, acc[dt], 0, 0, 0);
    }

    // ---- reduce row sum across the 4 g-lanes (same q=c) ----
    lsum += __shfl_xor(lsum, 16, 64);
    lsum += __shfl_xor(lsum, 32, 64);

    // ---- cross-slice combine ----
    if (slice > 0) {
        const int sidx = (slice - 1) * 2 + qh;
        #pragma unroll
        for (int dt = 0; dt < 4; ++dt)
            #pragma unroll
            for (int j = 0; j < 4; ++j)
                CombO[sidx][c][dt * 16 + g * 4 + j] = acc[dt][j];
        if (g == 0) {
            CombM[sidx][c] = mrow;
            CombL[sidx][c] = lsum;
        }
    }
    __syncthreads();

    if (slice == 0) {
        float M = mrow;
        #pragma unroll
        for (int s = 0; s < 3; ++s) M = fmaxf(M, CombM[s * 2 + qh][c]);
        const float a0 = __expf(mrow - M);
        float as[3];
        float lt = lsum * a0;
        #pragma unroll
        for (int s = 0; s < 3; ++s) {
            as[s] = __expf(CombM[s * 2 + qh][c] - M);
            lt += as[s] * CombL[s * 2 + qh][c];
        }
        const float linv = 1.0f / lt;
        #pragma unroll
        for (int dt = 0; dt < 4; ++dt) {
            float4 o;
            float* op = &o.x;
            #pragma unroll
            for (int j = 0; j < 4; ++j) {
                float v = acc[dt][j] * a0;
                #pragma unroll
                for (int s = 0; s < 3; ++s)
                    v += as[s] * CombO[s * 2 + qh][c][dt * 16 + g * 4 + j];
                op[j] = v * linv;
            }
            *(float4*)(out + bo + (size_t)(rbase + c) * 64 + dt * 16 + g * 4) = o;
        }
    }
}

extern "C" void kernel_launch(void* const* d_in, const int* in_sizes, int n_in,
                              void* d_out, int out_size, void* d_ws, size_t ws_size,
                              hipStream_t stream) {
    const float* x  = (const float*)d_in[0];
    const float* Wq = (const float*)d_in[1];
    const float* Wk = (const float*)d_in[2];
    const float* Wv = (const float*)d_in[3];

    unsigned short* Wt = (unsigned short*)d_ws;                        // 384 KiB (frag-major)
    unsigned short* q  = (unsigned short*)((char*)d_ws + (size_t)3 * 65536 * 2);
    unsigned short* kp = q + (size_t)4 * T_LEN * HSZ;                  // frag-major K, 2 MiB
    unsigned short* vp = kp + (size_t)4 * T_LEN * HSZ;                 // frag-major V, 2 MiB
    float* out = (float*)d_out;

    hipLaunchKernelGGL(wt_kernel,  dim3(768), dim3(256), 0, stream, Wq, Wk, Wv, Wt);
    hipLaunchKernelGGL(qkv_kernel, dim3(1024), dim3(256), 0, stream, x, Wt, q, kp, vp);
    hipLaunchKernelGGL(attn_kernel, dim3(512), dim3(512), 0, stream, q, kp, vp, out);
}

// Round 14
// 59.084 us; speedup vs baseline: 2.4228x; 1.1429x over previous
//
#include <hip/hip_runtime.h>
#include <stdint.h>

typedef __attribute__((ext_vector_type(8))) short short8v;
typedef __attribute__((ext_vector_type(4))) float float4v;

__device__ __forceinline__ unsigned short f32_to_bf16(float f) {
    union { float f; uint32_t u; } v; v.f = f;
    uint32_t u = v.u;
    u += 0x7FFFu + ((u >> 16) & 1u);
    return (unsigned short)(u >> 16);
}

#define T_LEN 4096
#define C_DIM 1024
#define HSZ 64

// ---------------- kernel 0: W -> Wtp (bf16, FRAGMENT-MAJOR) ----------------
__global__ void wt_kernel(const float* __restrict__ Wq, const float* __restrict__ Wk,
                          const float* __restrict__ Wv, unsigned short* __restrict__ Wtp) {
    int idx = blockIdx.x * blockDim.x + threadIdx.x;   // 0 .. 196607
    int e    = idx & 7;
    int lane = (idx >> 3) & 63;
    int ks   = (idx >> 9) & 31;
    int ct   = idx >> 14;
    int g = lane >> 4, c = lane & 15;
    int k   = ks * 32 + g * 8 + e;
    int col = (ct & 3) * 16 + c;
    int m   = ct >> 2;
    const float* W = (m == 0) ? Wq : ((m == 1) ? Wk : Wv);
    Wtp[idx] = f32_to_bf16(W[(size_t)k * 64 + col]);
}

// ---------------- kernel 1: fused QKV projection (staged x, frag-major Wtp) ----------------
#define XLD 1032   // 1024 + 8 pad

__global__ __launch_bounds__(256) void qkv_kernel(
    const float* __restrict__ x, const unsigned short* __restrict__ Wtp,
    unsigned short* __restrict__ qo, unsigned short* __restrict__ kp,
    unsigned short* __restrict__ vp)
{
    __shared__ __align__(16) unsigned short xs[16 * XLD];
    const int tid = threadIdx.x;
    const int bid = (int)blockIdx.x;
    const int rowidx = (((bid >> 1) & 3) << 8) + ((bid >> 3) << 1) + (bid & 1);
    const int row0 = rowidx * 16;

    #pragma unroll
    for (int i = 0; i < 16; ++i) {
        int f   = i * 256 + tid;           // float4 index, 4096 total
        int row = f >> 8, c4 = f & 255;
        const float4 val = *((const float4*)x + (size_t)(row0 + row) * 256 + c4);
        union { unsigned short s[4]; uint64_t u; } pk;
        pk.s[0] = f32_to_bf16(val.x); pk.s[1] = f32_to_bf16(val.y);
        pk.s[2] = f32_to_bf16(val.z); pk.s[3] = f32_to_bf16(val.w);
        *(uint64_t*)(&xs[row * XLD + c4 * 4]) = pk.u;
    }
    __syncthreads();

    const int wave = tid >> 6, lane = tid & 63;
    const int g = lane >> 4, c = lane & 15;

    float4v acc0 = {0,0,0,0}, acc1 = {0,0,0,0}, acc2 = {0,0,0,0};
    const unsigned short* wp0 = Wtp + (size_t)((wave * 3 + 0) * 32) * 512 + lane * 8;
    const unsigned short* wp1 = Wtp + (size_t)((wave * 3 + 1) * 32) * 512 + lane * 8;
    const unsigned short* wp2 = Wtp + (size_t)((wave * 3 + 2) * 32) * 512 + lane * 8;
    #pragma unroll 4
    for (int ks = 0; ks < 32; ++ks) {
        const int koff = ks * 32 + g * 8;
        short8v a  = *(const short8v*)(&xs[c * XLD + koff]);
        short8v b0 = *(const short8v*)(wp0 + ks * 512);   // contiguous 1 KB / wave
        short8v b1 = *(const short8v*)(wp1 + ks * 512);
        short8v b2 = *(const short8v*)(wp2 + ks * 512);
        acc0 = __builtin_amdgcn_mfma_f32_16x16x32_bf16(a, b0, acc0, 0, 0, 0);
        acc1 = __builtin_amdgcn_mfma_f32_16x16x32_bf16(a, b1, acc1, 0, 0, 0);
        acc2 = __builtin_amdgcn_mfma_f32_16x16x32_bf16(a, b2, acc2, 0, 0, 0);
    }

    float4v accs[3] = {acc0, acc1, acc2};
    #pragma unroll
    for (int t = 0; t < 3; ++t) {
        int ct = wave * 3 + t;
        int m = ct >> 2, hcol = (ct & 3) * 16 + c;
        if (m == 2) {
            // v -> fragment-major vp (R12-verified): j=0..3 -> one 8B store
            const int r0 = row0 + g * 4;
            const int b  = r0 >> 12;
            const int s0_ = r0 & 4095;
            const int t2h = s0_ >> 5;
            const int gv  = (s0_ >> 3) & 3;
            const int e0  = s0_ & 7;
            union { unsigned short s[4]; uint64_t u; } pk;
            #pragma unroll
            for (int j = 0; j < 4; ++j) pk.s[j] = f32_to_bf16(accs[t][j]);
            *(uint64_t*)(vp + (size_t)b * 262144 + t2h * 2048 + (ct & 3) * 512
                            + (gv * 16 + c) * 8 + e0) = pk.u;
        } else if (m == 1) {
            // K -> fragment-major kp (R13-verified)
            const int fbase = ((row0 & 4095) >> 6) * 8 + (((row0 & 4095) >> 4) & 3) * 2 + (hcol >> 5);
            const int b = row0 >> 12;
            unsigned short* kb = kp + (size_t)b * 262144 + (size_t)fbase * 512
                                 + (((hcol >> 3) & 3) * 16) * 8 + (hcol & 7);
            #pragma unroll
            for (int j = 0; j < 4; ++j)
                kb[(g * 4 + j) * 8] = f32_to_bf16(accs[t][j]);
        } else {
            float sc = 0.125f;   // fold 1/sqrt(64) into q
            #pragma unroll
            for (int j = 0; j < 4; ++j)
                qo[(size_t)(row0 + g * 4 + j) * 64 + hcol] = f32_to_bf16(accs[t][j] * sc);
        }
    }
}

// ---------------- kernel 2: causal flash attention ----------------
// Swapped QK^T, all-frag-major loads, K-fragment register double-buffer
// (prefetch tile t+4's kp frags during tile t's compute; no loop barriers so
// the overlap is real), packed b64 P writes.
#define PLD 72

__global__ __launch_bounds__(512) void attn_kernel(
    const unsigned short* __restrict__ qi, const unsigned short* __restrict__ kp,
    const unsigned short* __restrict__ vp, float* __restrict__ out)
{
    __shared__ __align__(16) unsigned short Ps[8][16 * PLD];  // per-wave P buffer
    __shared__ float CombO[6][16][64];                        // [slot][q-row][d]
    __shared__ float CombM[6][16];
    __shared__ float CombL[6][16];

    const int tid   = threadIdx.x;
    const int wave  = tid >> 6, lane = tid & 63;
    const int qh    = wave & 1, slice = wave >> 1;
    const int g = lane >> 4, c = lane & 15;

    const int bid   = (int)blockIdx.x;
    const int batch = (bid >> 1) & 3;     // XCD pair {2b,2b+1} = batch b
    const int q0    = bid & 1;
    const int m_    = bid >> 3;
    const int mm    = m_ & 31;
    const int qb = q0 ? ((m_ < 32) ? 2 * mm + 1 : 126 - 2 * mm)
                      : ((m_ < 32) ? 2 * mm     : 127 - 2 * mm);

    const int rbase = qb * 32 + qh * 16;
    const size_t bo  = (size_t)batch * T_LEN * HSZ;
    const size_t bov = (size_t)batch * 262144;

    short8v qf0 = *(const short8v*)(qi + bo + (size_t)(rbase + c) * 64 +  0 + g * 8);
    short8v qf1 = *(const short8v*)(qi + bo + (size_t)(rbase + c) * 64 + 32 + g * 8);

    float4v acc[4];   // acc[dt][j] = O^T[dt*16+g*4+j][q=rbase+c]
    #pragma unroll
    for (int i2 = 0; i2 < 4; ++i2) acc[i2] = (float4v){0,0,0,0};
    float mrow = -3e38f;   // per-lane: q = rbase+c
    float lsum = 0.f;

    const int nt_w = ((rbase + 15) >> 6) + 1;
    unsigned short* Pw = &Ps[wave][0];

    short8v kf[8], kn[8];

    // one tile's compute, K frags from registers
    auto TILE = [&](int t, const short8v* kb) {
        const int s0 = t * 64;

        float4v sa[4];
        #pragma unroll
        for (int ct = 0; ct < 4; ++ct) {
            float4v z = {0, 0, 0, 0};
            z = __builtin_amdgcn_mfma_f32_16x16x32_bf16(kb[ct * 2 + 0], qf0, z, 0, 0, 0);
            sa[ct] = __builtin_amdgcn_mfma_f32_16x16x32_bf16(kb[ct * 2 + 1], qf1, z, 0, 0, 0);
        }

        // first-half vp A-frags (used late; latency hides under softmax)
        short8v vf0[4];
        #pragma unroll
        for (int dt = 0; dt < 4; ++dt)
            vf0[dt] = *(const short8v*)(vp + bov + (size_t)(t * 8 + dt) * 512 + lane * 8);

        // causal mask: k = s0+ct*16+g*4+j vs q = rbase+c
        if (s0 + 63 > rbase) {
            #pragma unroll
            for (int ct = 0; ct < 4; ++ct)
                #pragma unroll
                for (int j = 0; j < 4; ++j)
                    if (s0 + ct * 16 + g * 4 + j > rbase + c) sa[ct][j] = -3e38f;
        }

        // online softmax: lane-local max tree + 2 shfl
        float mx01 = fmaxf(fmaxf(sa[0][0], sa[0][1]), fmaxf(sa[0][2], sa[0][3]));
        float mx11 = fmaxf(fmaxf(sa[1][0], sa[1][1]), fmaxf(sa[1][2], sa[1][3]));
        float mx21 = fmaxf(fmaxf(sa[2][0], sa[2][1]), fmaxf(sa[2][2], sa[2][3]));
        float mx31 = fmaxf(fmaxf(sa[3][0], sa[3][1]), fmaxf(sa[3][2], sa[3][3]));
        float mx = fmaxf(fmaxf(mx01, mx11), fmaxf(mx21, mx31));
        mx = fmaxf(mx, __shfl_xor(mx, 16, 64));
        mx = fmaxf(mx, __shfl_xor(mx, 32, 64));
        const float nm = fmaxf(mrow, mx);
        const float al = __expf(mrow - nm);
        mrow = nm;
        float ps = 0.f;
        #pragma unroll
        for (int ct = 0; ct < 4; ++ct)
            #pragma unroll
            for (int j = 0; j < 4; ++j) {
                float p = __expf(sa[ct][j] - nm);
                sa[ct][j] = p;
                ps += p;
            }
        lsum = lsum * al + ps;
        #pragma unroll
        for (int dt = 0; dt < 4; ++dt)
            #pragma unroll
            for (int j = 0; j < 4; ++j) acc[dt][j] *= al;

        // P^T -> per-wave LDS, PACKED b64 (j=0..3 contiguous, 8B-aligned)
        #pragma unroll
        for (int ct = 0; ct < 4; ++ct) {
            union { unsigned short s[4]; uint64_t u; } pk4;
            #pragma unroll
            for (int j = 0; j < 4; ++j) pk4.s[j] = f32_to_bf16(sa[ct][j]);
            *(uint64_t*)(&Pw[c * PLD + ct * 16 + g * 4]) = pk4.u;
        }

        // second-half vp A-frags
        short8v vf1[4];
        #pragma unroll
        for (int dt = 0; dt < 4; ++dt)
            vf1[dt] = *(const short8v*)(vp + bov + (size_t)(t * 8 + 4 + dt) * 512 + lane * 8);

        // P B-frags
        short8v pa0 = *(const short8v*)(&Pw[c * PLD +  0 + g * 8]);
        short8v pa1 = *(const short8v*)(&Pw[c * PLD + 32 + g * 8]);

        // O^T += vT P^T
        #pragma unroll
        for (int dt = 0; dt < 4; ++dt)
            acc[dt] = __builtin_amdgcn_mfma_f32_16x16x32_bf16(vf0[dt], pa0, acc[dt], 0, 0, 0);
        #pragma unroll
        for (int dt = 0; dt < 4; ++dt)
            acc[dt] = __builtin_amdgcn_mfma_f32_16x16x32_bf16(vf1[dt], pa1, acc[dt], 0, 0, 0);
    };

    auto LOADK = [&](int t, short8v* kd) {
        #pragma unroll
        for (int f = 0; f < 8; ++f)
            kd[f] = *(const short8v*)(kp + bov + (size_t)(t * 8 + f) * 512 + lane * 8);
    };

    // unrolled-by-2 ping-pong: prefetch t+4 while computing t (no reg copies)
    int t = slice;
    if (t < nt_w) {
        LOADK(t, kf);
        while (true) {
            const bool h1 = (t + 4 < nt_w);
            if (h1) LOADK(t + 4, kn);
            TILE(t, kf);
            if (!h1) break;
            t += 4;
            const bool h2 = (t + 4 < nt_w);
            if (h2) LOADK(t + 4, kf);
            TILE(t, kn);
            if (!h2) break;
            t += 4;
        }
    }

    // reduce row sum across the 4 g-lanes (same q=c)
    lsum += __shfl_xor(lsum, 16, 64);
    lsum += __shfl_xor(lsum, 32, 64);

    // cross-slice combine
    if (slice > 0) {
        const int sidx = (slice - 1) * 2 + qh;
        #pragma unroll
        for (int dt = 0; dt < 4; ++dt)
            #pragma unroll
            for (int j = 0; j < 4; ++j)
                CombO[sidx][c][dt * 16 + g * 4 + j] = acc[dt][j];
        if (g == 0) {
            CombM[sidx][c] = mrow;
            CombL[sidx][c] = lsum;
        }
    }
    __syncthreads();

    if (slice == 0) {
        float M = mrow;
        #pragma unroll
        for (int s = 0; s < 3; ++s) M = fmaxf(M, CombM[s * 2 + qh][c]);
        const float a0 = __expf(mrow - M);
        float as[3];
        float lt = lsum * a0;
        #pragma unroll
        for (int s = 0; s < 3; ++s) {
            as[s] = __expf(CombM[s * 2 + qh][c] - M);
            lt += as[s] * CombL[s * 2 + qh][c];
        }
        const float linv = 1.0f / lt;
        #pragma unroll
        for (int dt = 0; dt < 4; ++dt) {
            float4 o;
            float* op = &o.x;
            #pragma unroll
            for (int j = 0; j < 4; ++j) {
                float v = acc[dt][j] * a0;
                #pragma unroll
                for (int s = 0; s < 3; ++s)
                    v += as[s] * CombO[s * 2 + qh][c][dt * 16 + g * 4 + j];
                op[j] = v * linv;
            }
            *(float4*)(out + bo + (size_t)(rbase + c) * 64 + dt * 16 + g * 4) = o;
        }
    }
}

extern "C" void kernel_launch(void* const* d_in, const int* in_sizes, int n_in,
                              void* d_out, int out_size, void* d_ws, size_t ws_size,
                              hipStream_t stream) {
    const float* x  = (const float*)d_in[0];
    const float* Wq = (const float*)d_in[1];
    const float* Wk = (const float*)d_in[2];
    const float* Wv = (const float*)d_in[3];

    unsigned short* Wt = (unsigned short*)d_ws;                        // 384 KiB (frag-major)
    unsigned short* q  = (unsigned short*)((char*)d_ws + (size_t)3 * 65536 * 2);
    unsigned short* kp = q + (size_t)4 * T_LEN * HSZ;                  // frag-major K, 2 MiB
    unsigned short* vp = kp + (size_t)4 * T_LEN * HSZ;                 // frag-major V, 2 MiB
    float* out = (float*)d_out;

    hipLaunchKernelGGL(wt_kernel,  dim3(768), dim3(256), 0, stream, Wq, Wk, Wv, Wt);
    hipLaunchKernelGGL(qkv_kernel, dim3(1024), dim3(256), 0, stream, x, Wt, q, kp, vp);
    hipLaunchKernelGGL(attn_kernel, dim3(512), dim3(512), 0, stream, q, kp, vp, out);
}

// Round 15
// 57.834 us; speedup vs baseline: 2.4751x; 1.0216x over previous
//
#include <hip/hip_runtime.h>
#include <stdint.h>

typedef __attribute__((ext_vector_type(8))) short short8v;
typedef __attribute__((ext_vector_type(4))) float float4v;

__device__ __forceinline__ unsigned short f32_to_bf16(float f) {
    union { float f; uint32_t u; } v; v.f = f;
    uint32_t u = v.u;
    u += 0x7FFFu + ((u >> 16) & 1u);
    return (unsigned short)(u >> 16);
}

#define T_LEN 4096
#define C_DIM 1024
#define HSZ 64

// ---------------- kernel 0: W -> Wtp (bf16, FRAGMENT-MAJOR) ----------------
__global__ void wt_kernel(const float* __restrict__ Wq, const float* __restrict__ Wk,
                          const float* __restrict__ Wv, unsigned short* __restrict__ Wtp) {
    int idx = blockIdx.x * blockDim.x + threadIdx.x;   // 0 .. 196607
    int e    = idx & 7;
    int lane = (idx >> 3) & 63;
    int ks   = (idx >> 9) & 31;
    int ct   = idx >> 14;
    int g = lane >> 4, c = lane & 15;
    int k   = ks * 32 + g * 8 + e;
    int col = (ct & 3) * 16 + c;
    int m   = ct >> 2;
    const float* W = (m == 0) ? Wq : ((m == 1) ? Wk : Wv);
    Wtp[idx] = f32_to_bf16(W[(size_t)k * 64 + col]);
}

// ---------------- kernel 1: QKV projection, K-PIPELINED staging ----------------
// x staged in 4 column-chunks of 256 (double-buffered 17 KB LDS); chunk cs+1's
// global loads are in flight during chunk cs's MFMA phase.
#define XCH 264   // 256 + 8 pad (528 B row stride)

__global__ __launch_bounds__(256) void qkv_kernel(
    const float* __restrict__ x, const unsigned short* __restrict__ Wtp,
    unsigned short* __restrict__ qo, unsigned short* __restrict__ kp,
    unsigned short* __restrict__ vp)
{
    __shared__ __align__(16) unsigned short xs2[2][16 * XCH];
    const int tid = threadIdx.x;
    const int bid = (int)blockIdx.x;
    const int rowidx = (((bid >> 1) & 3) << 8) + ((bid >> 3) << 1) + (bid & 1);
    const int row0 = rowidx * 16;

    const int wave = tid >> 6, lane = tid & 63;
    const int g = lane >> 4, c = lane & 15;

    const int lrow = tid >> 6;            // staging coords: thread -> 4 chunks' f4
    float4 ld[4];

    auto LOADX = [&](int cs) {
        #pragma unroll
        for (int i = 0; i < 4; ++i) {
            int f = i * 256 + tid;        // 0..1023 f4 of the chunk
            int row = f >> 6, c4 = f & 63;
            ld[i] = *((const float4*)x + (size_t)(row0 + row) * 256 + cs * 64 + c4);
        }
    };
    auto WRITEX = [&](int buf) {
        #pragma unroll
        for (int i = 0; i < 4; ++i) {
            int f = i * 256 + tid;
            int row = f >> 6, c4 = f & 63;
            union { unsigned short s[4]; uint64_t u; } pk;
            pk.s[0] = f32_to_bf16(ld[i].x); pk.s[1] = f32_to_bf16(ld[i].y);
            pk.s[2] = f32_to_bf16(ld[i].z); pk.s[3] = f32_to_bf16(ld[i].w);
            *(uint64_t*)(&xs2[buf][row * XCH + c4 * 4]) = pk.u;
        }
    };
    (void)lrow;

    LOADX(0);
    WRITEX(0);
    __syncthreads();

    float4v acc0 = {0,0,0,0}, acc1 = {0,0,0,0}, acc2 = {0,0,0,0};
    const unsigned short* wp0 = Wtp + (size_t)((wave * 3 + 0) * 32) * 512 + lane * 8;
    const unsigned short* wp1 = Wtp + (size_t)((wave * 3 + 1) * 32) * 512 + lane * 8;
    const unsigned short* wp2 = Wtp + (size_t)((wave * 3 + 2) * 32) * 512 + lane * 8;

    for (int cs = 0; cs < 4; ++cs) {
        if (cs < 3) LOADX(cs + 1);        // loads in flight during the MFMA phase
        const int buf = cs & 1;
        #pragma unroll
        for (int k8 = 0; k8 < 8; ++k8) {
            const int ks = cs * 8 + k8;
            short8v a  = *(const short8v*)(&xs2[buf][c * XCH + k8 * 32 + g * 8]);
            short8v b0 = *(const short8v*)(wp0 + ks * 512);   // contiguous 1 KB / wave
            short8v b1 = *(const short8v*)(wp1 + ks * 512);
            short8v b2 = *(const short8v*)(wp2 + ks * 512);
            acc0 = __builtin_amdgcn_mfma_f32_16x16x32_bf16(a, b0, acc0, 0, 0, 0);
            acc1 = __builtin_amdgcn_mfma_f32_16x16x32_bf16(a, b1, acc1, 0, 0, 0);
            acc2 = __builtin_amdgcn_mfma_f32_16x16x32_bf16(a, b2, acc2, 0, 0, 0);
        }
        if (cs < 3) {
            __syncthreads();              // all waves done reading buf^1 (chunk cs-1)
            WRITEX(buf ^ 1);
            __syncthreads();              // writes visible before next chunk's reads
        }
    }

    float4v accs[3] = {acc0, acc1, acc2};
    #pragma unroll
    for (int t = 0; t < 3; ++t) {
        int ct = wave * 3 + t;
        int m = ct >> 2, hcol = (ct & 3) * 16 + c;
        if (m == 2) {
            // v -> fragment-major vp (R12-verified): j=0..3 -> one 8B store
            const int r0 = row0 + g * 4;
            const int b  = r0 >> 12;
            const int s0_ = r0 & 4095;
            const int t2h = s0_ >> 5;
            const int gv  = (s0_ >> 3) & 3;
            const int e0  = s0_ & 7;
            union { unsigned short s[4]; uint64_t u; } pk;
            #pragma unroll
            for (int j = 0; j < 4; ++j) pk.s[j] = f32_to_bf16(accs[t][j]);
            *(uint64_t*)(vp + (size_t)b * 262144 + t2h * 2048 + (ct & 3) * 512
                            + (gv * 16 + c) * 8 + e0) = pk.u;
        } else if (m == 1) {
            // K -> fragment-major kp (R13-verified)
            const int fbase = ((row0 & 4095) >> 6) * 8 + (((row0 & 4095) >> 4) & 3) * 2 + (hcol >> 5);
            const int b = row0 >> 12;
            unsigned short* kb = kp + (size_t)b * 262144 + (size_t)fbase * 512
                                 + (((hcol >> 3) & 3) * 16) * 8 + (hcol & 7);
            #pragma unroll
            for (int j = 0; j < 4; ++j)
                kb[(g * 4 + j) * 8] = f32_to_bf16(accs[t][j]);
        } else {
            float sc = 0.125f;   // fold 1/sqrt(64) into q
            #pragma unroll
            for (int j = 0; j < 4; ++j)
                qo[(size_t)(row0 + g * 4 + j) * 64 + hcol] = f32_to_bf16(accs[t][j] * sc);
        }
    }
}

// ---------------- kernel 2: causal flash attention (R14, unchanged) ----------------
#define PLD 72

__global__ __launch_bounds__(512) void attn_kernel(
    const unsigned short* __restrict__ qi, const unsigned short* __restrict__ kp,
    const unsigned short* __restrict__ vp, float* __restrict__ out)
{
    __shared__ __align__(16) unsigned short Ps[8][16 * PLD];  // per-wave P buffer
    __shared__ float CombO[6][16][64];                        // [slot][q-row][d]
    __shared__ float CombM[6][16];
    __shared__ float CombL[6][16];

    const int tid   = threadIdx.x;
    const int wave  = tid >> 6, lane = tid & 63;
    const int qh    = wave & 1, slice = wave >> 1;
    const int g = lane >> 4, c = lane & 15;

    const int bid   = (int)blockIdx.x;
    const int batch = (bid >> 1) & 3;     // XCD pair {2b,2b+1} = batch b
    const int q0    = bid & 1;
    const int m_    = bid >> 3;
    const int mm    = m_ & 31;
    const int qb = q0 ? ((m_ < 32) ? 2 * mm + 1 : 126 - 2 * mm)
                      : ((m_ < 32) ? 2 * mm     : 127 - 2 * mm);

    const int rbase = qb * 32 + qh * 16;
    const size_t bo  = (size_t)batch * T_LEN * HSZ;
    const size_t bov = (size_t)batch * 262144;

    short8v qf0 = *(const short8v*)(qi + bo + (size_t)(rbase + c) * 64 +  0 + g * 8);
    short8v qf1 = *(const short8v*)(qi + bo + (size_t)(rbase + c) * 64 + 32 + g * 8);

    float4v acc[4];   // acc[dt][j] = O^T[dt*16+g*4+j][q=rbase+c]
    #pragma unroll
    for (int i2 = 0; i2 < 4; ++i2) acc[i2] = (float4v){0,0,0,0};
    float mrow = -3e38f;   // per-lane: q = rbase+c
    float lsum = 0.f;

    const int nt_w = ((rbase + 15) >> 6) + 1;
    unsigned short* Pw = &Ps[wave][0];

    short8v kf[8], kn[8];

    auto TILE = [&](int t, const short8v* kb) {
        const int s0 = t * 64;

        float4v sa[4];
        #pragma unroll
        for (int ct = 0; ct < 4; ++ct) {
            float4v z = {0, 0, 0, 0};
            z = __builtin_amdgcn_mfma_f32_16x16x32_bf16(kb[ct * 2 + 0], qf0, z, 0, 0, 0);
            sa[ct] = __builtin_amdgcn_mfma_f32_16x16x32_bf16(kb[ct * 2 + 1], qf1, z, 0, 0, 0);
        }

        short8v vf0[4];
        #pragma unroll
        for (int dt = 0; dt < 4; ++dt)
            vf0[dt] = *(const short8v*)(vp + bov + (size_t)(t * 8 + dt) * 512 + lane * 8);

        if (s0 + 63 > rbase) {
            #pragma unroll
            for (int ct = 0; ct < 4; ++ct)
                #pragma unroll
                for (int j = 0; j < 4; ++j)
                    if (s0 + ct * 16 + g * 4 + j > rbase + c) sa[ct][j] = -3e38f;
        }

        float mx01 = fmaxf(fmaxf(sa[0][0], sa[0][1]), fmaxf(sa[0][2], sa[0][3]));
        float mx11 = fmaxf(fmaxf(sa[1][0], sa[1][1]), fmaxf(sa[1][2], sa[1][3]));
        float mx21 = fmaxf(fmaxf(sa[2][0], sa[2][1]), fmaxf(sa[2][2], sa[2][3]));
        float mx31 = fmaxf(fmaxf(sa[3][0], sa[3][1]), fmaxf(sa[3][2], sa[3][3]));
        float mx = fmaxf(fmaxf(mx01, mx11), fmaxf(mx21, mx31));
        mx = fmaxf(mx, __shfl_xor(mx, 16, 64));
        mx = fmaxf(mx, __shfl_xor(mx, 32, 64));
        const float nm = fmaxf(mrow, mx);
        const float al = __expf(mrow - nm);
        mrow = nm;
        float ps = 0.f;
        #pragma unroll
        for (int ct = 0; ct < 4; ++ct)
            #pragma unroll
            for (int j = 0; j < 4; ++j) {
                float p = __expf(sa[ct][j] - nm);
                sa[ct][j] = p;
                ps += p;
            }
        lsum = lsum * al + ps;
        #pragma unroll
        for (int dt = 0; dt < 4; ++dt)
            #pragma unroll
            for (int j = 0; j < 4; ++j) acc[dt][j] *= al;

        #pragma unroll
        for (int ct = 0; ct < 4; ++ct) {
            union { unsigned short s[4]; uint64_t u; } pk4;
            #pragma unroll
            for (int j = 0; j < 4; ++j) pk4.s[j] = f32_to_bf16(sa[ct][j]);
            *(uint64_t*)(&Pw[c * PLD + ct * 16 + g * 4]) = pk4.u;
        }

        short8v vf1[4];
        #pragma unroll
        for (int dt = 0; dt < 4; ++dt)
            vf1[dt] = *(const short8v*)(vp + bov + (size_t)(t * 8 + 4 + dt) * 512 + lane * 8);

        short8v pa0 = *(const short8v*)(&Pw[c * PLD +  0 + g * 8]);
        short8v pa1 = *(const short8v*)(&Pw[c * PLD + 32 + g * 8]);

        #pragma unroll
        for (int dt = 0; dt < 4; ++dt)
            acc[dt] = __builtin_amdgcn_mfma_f32_16x16x32_bf16(vf0[dt], pa0, acc[dt], 0, 0, 0);
        #pragma unroll
        for (int dt = 0; dt < 4; ++dt)
            acc[dt] = __builtin_amdgcn_mfma_f32_16x16x32_bf16(vf1[dt], pa1, acc[dt], 0, 0, 0);
    };

    auto LOADK = [&](int t, short8v* kd) {
        #pragma unroll
        for (int f = 0; f < 8; ++f)
            kd[f] = *(const short8v*)(kp + bov + (size_t)(t * 8 + f) * 512 + lane * 8);
    };

    int t = slice;
    if (t < nt_w) {
        LOADK(t, kf);
        while (true) {
            const bool h1 = (t + 4 < nt_w);
            if (h1) LOADK(t + 4, kn);
            TILE(t, kf);
            if (!h1) break;
            t += 4;
            const bool h2 = (t + 4 < nt_w);
            if (h2) LOADK(t + 4, kf);
            TILE(t, kn);
            if (!h2) break;
            t += 4;
        }
    }

    lsum += __shfl_xor(lsum, 16, 64);
    lsum += __shfl_xor(lsum, 32, 64);

    if (slice > 0) {
        const int sidx = (slice - 1) * 2 + qh;
        #pragma unroll
        for (int dt = 0; dt < 4; ++dt)
            #pragma unroll
            for (int j = 0; j < 4; ++j)
                CombO[sidx][c][dt * 16 + g * 4 + j] = acc[dt][j];
        if (g == 0) {
            CombM[sidx][c] = mrow;
            CombL[sidx][c] = lsum;
        }
    }
    __syncthreads();

    if (slice == 0) {
        float M = mrow;
        #pragma unroll
        for (int s = 0; s < 3; ++s) M = fmaxf(M, CombM[s * 2 + qh][c]);
        const float a0 = __expf(mrow - M);
        float as[3];
        float lt = lsum * a0;
        #pragma unroll
        for (int s = 0; s < 3; ++s) {
            as[s] = __expf(CombM[s * 2 + qh][c] - M);
            lt += as[s] * CombL[s * 2 + qh][c];
        }
        const float linv = 1.0f / lt;
        #pragma unroll
        for (int dt = 0; dt < 4; ++dt) {
            float4 o;
            float* op = &o.x;
            #pragma unroll
            for (int j = 0; j < 4; ++j) {
                float v = acc[dt][j] * a0;
                #pragma unroll
                for (int s = 0; s < 3; ++s)
                    v += as[s] * CombO[s * 2 + qh][c][dt * 16 + g * 4 + j];
                op[j] = v * linv;
            }
            *(float4*)(out + bo + (size_t)(rbase + c) * 64 + dt * 16 + g * 4) = o;
        }
    }
}

extern "C" void kernel_launch(void* const* d_in, const int* in_sizes, int n_in,
                              void* d_out, int out_size, void* d_ws, size_t ws_size,
                              hipStream_t stream) {
    const float* x  = (const float*)d_in[0];
    const float* Wq = (const float*)d_in[1];
    const float* Wk = (const float*)d_in[2];
    const float* Wv = (const float*)d_in[3];

    unsigned short* Wt = (unsigned short*)d_ws;                        // 384 KiB (frag-major)
    unsigned short* q  = (unsigned short*)((char*)d_ws + (size_t)3 * 65536 * 2);
    unsigned short* kp = q + (size_t)4 * T_LEN * HSZ;                  // frag-major K, 2 MiB
    unsigned short* vp = kp + (size_t)4 * T_LEN * HSZ;                 // frag-major V, 2 MiB
    float* out = (float*)d_out;

    hipLaunchKernelGGL(wt_kernel,  dim3(768), dim3(256), 0, stream, Wq, Wk, Wv, Wt);
    hipLaunchKernelGGL(qkv_kernel, dim3(1024), dim3(256), 0, stream, x, Wt, q, kp, vp);
    hipLaunchKernelGGL(attn_kernel, dim3(512), dim3(512), 0, stream, q, kp, vp, out);
}

// Round 16
// 52.855 us; speedup vs baseline: 2.7083x; 1.0942x over previous
//
#include <hip/hip_runtime.h>
#include <stdint.h>

typedef __attribute__((ext_vector_type(8))) short short8v;
typedef __attribute__((ext_vector_type(4))) float float4v;

__device__ __forceinline__ unsigned short f32_to_bf16(float f) {
    union { float f; uint32_t u; } v; v.f = f;
    uint32_t u = v.u;
    u += 0x7FFFu + ((u >> 16) & 1u);
    return (unsigned short)(u >> 16);
}

#define T_LEN 4096
#define C_DIM 1024
#define HSZ 64

// ---------------- kernel 0: W -> Wtp (bf16, FRAGMENT-MAJOR) ----------------
__global__ void wt_kernel(const float* __restrict__ Wq, const float* __restrict__ Wk,
                          const float* __restrict__ Wv, unsigned short* __restrict__ Wtp) {
    int idx = blockIdx.x * blockDim.x + threadIdx.x;   // 0 .. 196607
    int e    = idx & 7;
    int lane = (idx >> 3) & 63;
    int ks   = (idx >> 9) & 31;
    int ct   = idx >> 14;
    int g = lane >> 4, c = lane & 15;
    int k   = ks * 32 + g * 8 + e;
    int col = (ct & 3) * 16 + c;
    int m   = ct >> 2;
    const float* W = (m == 0) ? Wq : ((m == 1) ? Wk : Wv);
    Wtp[idx] = f32_to_bf16(W[(size_t)k * 64 + col]);
}

// ---------------- kernel 1: QKV projection, 32-row blocks + even/odd split-K ----------------
// Each wave (wq, wh) computes 2 row-tiles x 3 output-cts over ks ≡ wh (mod 2):
// Wtp B-frags amortized over 32 rows (L2 traffic halved vs 16-row blocks).
// Chunked x staging pipeline (R15); split-K combine via LDS (R8 pattern).
#define XCH 264   // 256 + 8 pad

__global__ __launch_bounds__(512) void qkv_kernel(
    const float* __restrict__ x, const unsigned short* __restrict__ Wtp,
    unsigned short* __restrict__ qo, unsigned short* __restrict__ kp,
    unsigned short* __restrict__ vp)
{
    __shared__ __align__(16) unsigned short xs2[2][32 * XCH];   // 33 KB
    __shared__ float part[4][2][3][64][4];                       // 24.6 KB split-K combine

    const int tid = threadIdx.x;
    const int bid = (int)blockIdx.x;
    const int batch = (bid >> 1) & 3;        // XCD-pinned (bid%8 -> XCD)
    const int q0    = bid & 1;
    const int hi    = bid >> 3;              // [0,64)
    const int rg    = hi * 2 + q0;           // [0,128) row-group of 32
    const int row0  = batch * 4096 + rg * 32;   // global row base (32-aligned)

    const int wave = tid >> 6, lane = tid & 63;
    const int wq = wave & 3, wh = wave >> 2;
    const int g = lane >> 4, c = lane & 15;

    float4 ld[4];
    auto LOADX = [&](int cs) {
        #pragma unroll
        for (int i = 0; i < 4; ++i) {
            int f = i * 512 + tid;           // 2048 f4 per 32x256 chunk
            int row = f >> 6, c4 = f & 63;
            ld[i] = *((const float4*)x + (size_t)(row0 + row) * 256 + cs * 64 + c4);
        }
    };
    auto WRITEX = [&](int buf) {
        #pragma unroll
        for (int i = 0; i < 4; ++i) {
            int f = i * 512 + tid;
            int row = f >> 6, c4 = f & 63;
            union { unsigned short s[4]; uint64_t u; } pk;
            pk.s[0] = f32_to_bf16(ld[i].x); pk.s[1] = f32_to_bf16(ld[i].y);
            pk.s[2] = f32_to_bf16(ld[i].z); pk.s[3] = f32_to_bf16(ld[i].w);
            *(uint64_t*)(&xs2[buf][row * XCH + c4 * 4]) = pk.u;
        }
    };

    LOADX(0);
    WRITEX(0);
    __syncthreads();

    float4v acc[2][3];
    #pragma unroll
    for (int rt = 0; rt < 2; ++rt)
        #pragma unroll
        for (int t = 0; t < 3; ++t) acc[rt][t] = (float4v){0,0,0,0};

    const unsigned short* wp0 = Wtp + (size_t)((wq * 3 + 0) * 32) * 512 + lane * 8;
    const unsigned short* wp1 = Wtp + (size_t)((wq * 3 + 1) * 32) * 512 + lane * 8;
    const unsigned short* wp2 = Wtp + (size_t)((wq * 3 + 2) * 32) * 512 + lane * 8;

    for (int cs = 0; cs < 4; ++cs) {
        if (cs < 3) LOADX(cs + 1);           // loads in flight during MFMA phase
        const int buf = cs & 1;
        #pragma unroll
        for (int ksi = 0; ksi < 4; ++ksi) {
            const int kc = 2 * ksi + wh;     // ks within chunk (even/odd split)
            const int ks = cs * 8 + kc;      // global ks
            const int koff = kc * 32 + g * 8;
            short8v a0 = *(const short8v*)(&xs2[buf][(0 * 16 + c) * XCH + koff]);
            short8v a1 = *(const short8v*)(&xs2[buf][(1 * 16 + c) * XCH + koff]);
            short8v b0 = *(const short8v*)(wp0 + (size_t)ks * 512);   // 1 KB contiguous
            short8v b1 = *(const short8v*)(wp1 + (size_t)ks * 512);
            short8v b2 = *(const short8v*)(wp2 + (size_t)ks * 512);
            acc[0][0] = __builtin_amdgcn_mfma_f32_16x16x32_bf16(a0, b0, acc[0][0], 0, 0, 0);
            acc[0][1] = __builtin_amdgcn_mfma_f32_16x16x32_bf16(a0, b1, acc[0][1], 0, 0, 0);
            acc[0][2] = __builtin_amdgcn_mfma_f32_16x16x32_bf16(a0, b2, acc[0][2], 0, 0, 0);
            acc[1][0] = __builtin_amdgcn_mfma_f32_16x16x32_bf16(a1, b0, acc[1][0], 0, 0, 0);
            acc[1][1] = __builtin_amdgcn_mfma_f32_16x16x32_bf16(a1, b1, acc[1][1], 0, 0, 0);
            acc[1][2] = __builtin_amdgcn_mfma_f32_16x16x32_bf16(a1, b2, acc[1][2], 0, 0, 0);
        }
        if (cs < 3) {
            __syncthreads();                 // all waves done reading buf^1
            WRITEX(buf ^ 1);
            __syncthreads();                 // writes visible before next reads
        }
    }

    // ---- split-K combine through LDS (wh=1 -> wh=0) ----
    __syncthreads();
    if (wh == 1) {
        #pragma unroll
        for (int rt = 0; rt < 2; ++rt)
            #pragma unroll
            for (int t = 0; t < 3; ++t)
                #pragma unroll
                for (int j = 0; j < 4; ++j)
                    part[wq][rt][t][lane][j] = acc[rt][t][j];
    }
    __syncthreads();
    if (wh == 0) {
        #pragma unroll
        for (int rt = 0; rt < 2; ++rt) {
            const int row0t = row0 + rt * 16;    // 16-aligned tile base
            #pragma unroll
            for (int t = 0; t < 3; ++t) {
                float4v av = acc[rt][t];
                #pragma unroll
                for (int j = 0; j < 4; ++j) av[j] += part[wq][rt][t][lane][j];
                int ct = wq * 3 + t;
                int m = ct >> 2, hcol = (ct & 3) * 16 + c;
                if (m == 2) {
                    // v -> fragment-major vp (R12-verified): one 8B store
                    const int r0 = row0t + g * 4;
                    const int b  = r0 >> 12;
                    const int s0_ = r0 & 4095;
                    const int t2h = s0_ >> 5;
                    const int gv  = (s0_ >> 3) & 3;
                    const int e0  = s0_ & 7;
                    union { unsigned short s[4]; uint64_t u; } pk;
                    #pragma unroll
                    for (int j = 0; j < 4; ++j) pk.s[j] = f32_to_bf16(av[j]);
                    *(uint64_t*)(vp + (size_t)b * 262144 + t2h * 2048 + (ct & 3) * 512
                                    + (gv * 16 + c) * 8 + e0) = pk.u;
                } else if (m == 1) {
                    // K -> fragment-major kp (R13-verified)
                    const int fbase = ((row0t & 4095) >> 6) * 8 + (((row0t & 4095) >> 4) & 3) * 2 + (hcol >> 5);
                    const int b = row0t >> 12;
                    unsigned short* kb = kp + (size_t)b * 262144 + (size_t)fbase * 512
                                         + (((hcol >> 3) & 3) * 16) * 8 + (hcol & 7);
                    #pragma unroll
                    for (int j = 0; j < 4; ++j)
                        kb[(g * 4 + j) * 8] = f32_to_bf16(av[j]);
                } else {
                    float sc = 0.125f;   // fold 1/sqrt(64) into q
                    #pragma unroll
                    for (int j = 0; j < 4; ++j)
                        qo[(size_t)(row0t + g * 4 + j) * 64 + hcol] = f32_to_bf16(av[j] * sc);
                }
            }
        }
    }
}

// ---------------- kernel 2: causal flash attention (R14, unchanged) ----------------
#define PLD 72

__global__ __launch_bounds__(512) void attn_kernel(
    const unsigned short* __restrict__ qi, const unsigned short* __restrict__ kp,
    const unsigned short* __restrict__ vp, float* __restrict__ out)
{
    __shared__ __align__(16) unsigned short Ps[8][16 * PLD];  // per-wave P buffer
    __shared__ float CombO[6][16][64];                        // [slot][q-row][d]
    __shared__ float CombM[6][16];
    __shared__ float CombL[6][16];

    const int tid   = threadIdx.x;
    const int wave  = tid >> 6, lane = tid & 63;
    const int qh    = wave & 1, slice = wave >> 1;
    const int g = lane >> 4, c = lane & 15;

    const int bid   = (int)blockIdx.x;
    const int batch = (bid >> 1) & 3;     // XCD pair {2b,2b+1} = batch b
    const int q0    = bid & 1;
    const int m_    = bid >> 3;
    const int mm    = m_ & 31;
    const int qb = q0 ? ((m_ < 32) ? 2 * mm + 1 : 126 - 2 * mm)
                      : ((m_ < 32) ? 2 * mm     : 127 - 2 * mm);

    const int rbase = qb * 32 + qh * 16;
    const size_t bo  = (size_t)batch * T_LEN * HSZ;
    const size_t bov = (size_t)batch * 262144;

    short8v qf0 = *(const short8v*)(qi + bo + (size_t)(rbase + c) * 64 +  0 + g * 8);
    short8v qf1 = *(const short8v*)(qi + bo + (size_t)(rbase + c) * 64 + 32 + g * 8);

    float4v acc[4];   // acc[dt][j] = O^T[dt*16+g*4+j][q=rbase+c]
    #pragma unroll
    for (int i2 = 0; i2 < 4; ++i2) acc[i2] = (float4v){0,0,0,0};
    float mrow = -3e38f;   // per-lane: q = rbase+c
    float lsum = 0.f;

    const int nt_w = ((rbase + 15) >> 6) + 1;
    unsigned short* Pw = &Ps[wave][0];

    short8v kf[8], kn[8];

    auto TILE = [&](int t, const short8v* kb) {
        const int s0 = t * 64;

        float4v sa[4];
        #pragma unroll
        for (int ct = 0; ct < 4; ++ct) {
            float4v z = {0, 0, 0, 0};
            z = __builtin_amdgcn_mfma_f32_16x16x32_bf16(kb[ct * 2 + 0], qf0, z, 0, 0, 0);
            sa[ct] = __builtin_amdgcn_mfma_f32_16x16x32_bf16(kb[ct * 2 + 1], qf1, z, 0, 0, 0);
        }

        short8v vf0[4];
        #pragma unroll
        for (int dt = 0; dt < 4; ++dt)
            vf0[dt] = *(const short8v*)(vp + bov + (size_t)(t * 8 + dt) * 512 + lane * 8);

        if (s0 + 63 > rbase) {
            #pragma unroll
            for (int ct = 0; ct < 4; ++ct)
                #pragma unroll
                for (int j = 0; j < 4; ++j)
                    if (s0 + ct * 16 + g * 4 + j > rbase + c) sa[ct][j] = -3e38f;
        }

        float mx01 = fmaxf(fmaxf(sa[0][0], sa[0][1]), fmaxf(sa[0][2], sa[0][3]));
        float mx11 = fmaxf(fmaxf(sa[1][0], sa[1][1]), fmaxf(sa[1][2], sa[1][3]));
        float mx21 = fmaxf(fmaxf(sa[2][0], sa[2][1]), fmaxf(sa[2][2], sa[2][3]));
        float mx31 = fmaxf(fmaxf(sa[3][0], sa[3][1]), fmaxf(sa[3][2], sa[3][3]));
        float mx = fmaxf(fmaxf(mx01, mx11), fmaxf(mx21, mx31));
        mx = fmaxf(mx, __shfl_xor(mx, 16, 64));
        mx = fmaxf(mx, __shfl_xor(mx, 32, 64));
        const float nm = fmaxf(mrow, mx);
        const float al = __expf(mrow - nm);
        mrow = nm;
        float ps = 0.f;
        #pragma unroll
        for (int ct = 0; ct < 4; ++ct)
            #pragma unroll
            for (int j = 0; j < 4; ++j) {
                float p = __expf(sa[ct][j] - nm);
                sa[ct][j] = p;
                ps += p;
            }
        lsum = lsum * al + ps;
        #pragma unroll
        for (int dt = 0; dt < 4; ++dt)
            #pragma unroll
            for (int j = 0; j < 4; ++j) acc[dt][j] *= al;

        #pragma unroll
        for (int ct = 0; ct < 4; ++ct) {
            union { unsigned short s[4]; uint64_t u; } pk4;
            #pragma unroll
            for (int j = 0; j < 4; ++j) pk4.s[j] = f32_to_bf16(sa[ct][j]);
            *(uint64_t*)(&Pw[c * PLD + ct * 16 + g * 4]) = pk4.u;
        }

        short8v vf1[4];
        #pragma unroll
        for (int dt = 0; dt < 4; ++dt)
            vf1[dt] = *(const short8v*)(vp + bov + (size_t)(t * 8 + 4 + dt) * 512 + lane * 8);

        short8v pa0 = *(const short8v*)(&Pw[c * PLD +  0 + g * 8]);
        short8v pa1 = *(const short8v*)(&Pw[c * PLD + 32 + g * 8]);

        #pragma unroll
        for (int dt = 0; dt < 4; ++dt)
            acc[dt] = __builtin_amdgcn_mfma_f32_16x16x32_bf16(vf0[dt], pa0, acc[dt], 0, 0, 0);
        #pragma unroll
        for (int dt = 0; dt < 4; ++dt)
            acc[dt] = __builtin_amdgcn_mfma_f32_16x16x32_bf16(vf1[dt], pa1, acc[dt], 0, 0, 0);
    };

    auto LOADK = [&](int t, short8v* kd) {
        #pragma unroll
        for (int f = 0; f < 8; ++f)
            kd[f] = *(const short8v*)(kp + bov + (size_t)(t * 8 + f) * 512 + lane * 8);
    };

    int t = slice;
    if (t < nt_w) {
        LOADK(t, kf);
        while (true) {
            const bool h1 = (t + 4 < nt_w);
            if (h1) LOADK(t + 4, kn);
            TILE(t, kf);
            if (!h1) break;
            t += 4;
            const bool h2 = (t + 4 < nt_w);
            if (h2) LOADK(t + 4, kf);
            TILE(t, kn);
            if (!h2) break;
            t += 4;
        }
    }

    lsum += __shfl_xor(lsum, 16, 64);
    lsum += __shfl_xor(lsum, 32, 64);

    if (slice > 0) {
        const int sidx = (slice - 1) * 2 + qh;
        #pragma unroll
        for (int dt = 0; dt < 4; ++dt)
            #pragma unroll
            for (int j = 0; j < 4; ++j)
                CombO[sidx][c][dt * 16 + g * 4 + j] = acc[dt][j];
        if (g == 0) {
            CombM[sidx][c] = mrow;
            CombL[sidx][c] = lsum;
        }
    }
    __syncthreads();

    if (slice == 0) {
        float M = mrow;
        #pragma unroll
        for (int s = 0; s < 3; ++s) M = fmaxf(M, CombM[s * 2 + qh][c]);
        const float a0 = __expf(mrow - M);
        float as[3];
        float lt = lsum * a0;
        #pragma unroll
        for (int s = 0; s < 3; ++s) {
            as[s] = __expf(CombM[s * 2 + qh][c] - M);
            lt += as[s] * CombL[s * 2 + qh][c];
        }
        const float linv = 1.0f / lt;
        #pragma unroll
        for (int dt = 0; dt < 4; ++dt) {
            float4 o;
            float* op = &o.x;
            #pragma unroll
            for (int j = 0; j < 4; ++j) {
                float v = acc[dt][j] * a0;
                #pragma unroll
                for (int s = 0; s < 3; ++s)
                    v += as[s] * CombO[s * 2 + qh][c][dt * 16 + g * 4 + j];
                op[j] = v * linv;
            }
            *(float4*)(out + bo + (size_t)(rbase + c) * 64 + dt * 16 + g * 4) = o;
        }
    }
}

extern "C" void kernel_launch(void* const* d_in, const int* in_sizes, int n_in,
                              void* d_out, int out_size, void* d_ws, size_t ws_size,
                              hipStream_t stream) {
    const float* x  = (const float*)d_in[0];
    const float* Wq = (const float*)d_in[1];
    const float* Wk = (const float*)d_in[2];
    const float* Wv = (const float*)d_in[3];

    unsigned short* Wt = (unsigned short*)d_ws;                        // 384 KiB (frag-major)
    unsigned short* q  = (unsigned short*)((char*)d_ws + (size_t)3 * 65536 * 2);
    unsigned short* kp = q + (size_t)4 * T_LEN * HSZ;                  // frag-major K, 2 MiB
    unsigned short* vp = kp + (size_t)4 * T_LEN * HSZ;                 // frag-major V, 2 MiB
    float* out = (float*)d_out;

    hipLaunchKernelGGL(wt_kernel,  dim3(768), dim3(256), 0, stream, Wq, Wk, Wv, Wt);
    hipLaunchKernelGGL(qkv_kernel, dim3(512), dim3(512), 0, stream, x, Wt, q, kp, vp);
    hipLaunchKernelGGL(attn_kernel, dim3(512), dim3(512), 0, stream, q, kp, vp, out);
}